// Round 3
// baseline (39.434 us; speedup 1.0000x reference)
//
#include <hip/hip_runtime.h>
#include <math.h>

#define N_I 1152
#define N_O 10
#define N_D 16
#define BLK 512
#define KPT 9   // i-rows per thread: 1152 / (BLK/4)

// One block per (b, o-PAIR): handles o0=2*op and o0+1 so every 128B cache
// line (which spans exactly two adjacent o's 64B slices) is fully consumed
// by ONE block -> no dependence on inter-block L2 timing for line reuse.
// Each thread holds 2 x 9 x float4 of u in registers (~72 data VGPRs).
// r=0 accumulation is fused into the load loop so compute starts under
// vmcnt as loads arrive. LDS is ~1.2 KB scratch; occupancy VGPR-bound at
// 2 blocks/CU (16 waves).
__global__ __launch_bounds__(BLK, 4)
void caps_route(const float* __restrict__ u_hat, float* __restrict__ out)
{
    __shared__ float scr_s[2][8][16];             // per-o per-wave partial s
    __shared__ float scr_e[2][8];                 // per-o per-wave exp-sum
    __shared__ __align__(16) float vcum[2][16];   // per-o cumulative v

    const int tid  = threadIdx.x;
    const int wave = tid >> 6;
    const int lane = tid & 63;
    const int d4   = tid & 3;
    const int ig   = tid >> 2;    // 0..127

    const int bid = blockIdx.x;
    const int nwg = gridDim.x;
    int wid = bid;
    if ((nwg & 7) == 0) wid = (bid & 7) * (nwg >> 3) + (bid >> 3);
    const int b  = wid / 5;       // 5 o-pairs per batch element
    const int op = wid - b * 5;
    const int o0 = op * 2;

    const float* gbase = u_hat + (size_t)b * (N_I * N_O * N_D)
                               + (size_t)o0 * N_D + d4 * 4;

    // ---- global -> registers; fuse r=0 partial sums into the load loop ----
    float4 u[2][KPT];
    float4 s4[2];
    s4[0] = make_float4(0.f, 0.f, 0.f, 0.f);
    s4[1] = make_float4(0.f, 0.f, 0.f, 0.f);
    #pragma unroll
    for (int k = 0; k < KPT; ++k) {
        const int i = ig + (k << 7);
        const float* g = gbase + (size_t)i * (N_O * N_D);
        u[0][k] = *(const float4*)(g);
        u[1][k] = *(const float4*)(g + N_D);
        s4[0].x += u[0][k].x; s4[0].y += u[0][k].y;
        s4[0].z += u[0][k].z; s4[0].w += u[0][k].w;
        s4[1].x += u[1][k].x; s4[1].y += u[1][k].y;
        s4[1].z += u[1][k].z; s4[1].w += u[1][k].w;
    }
    if (tid < 32) vcum[tid >> 4][tid & 15] = 0.0f;

    float4 vc[2];
    vc[0] = make_float4(0.f, 0.f, 0.f, 0.f);
    vc[1] = make_float4(0.f, 0.f, 0.f, 0.f);

    for (int r = 0; r < 3; ++r) {
        float esum[2];
        if (r == 0) {
            esum[0] = (float)KPT; esum[1] = (float)KPT;
        } else {
            #pragma unroll
            for (int j = 0; j < 2; ++j) {
                s4[j] = make_float4(0.f, 0.f, 0.f, 0.f);
                esum[j] = 0.0f;
            }
            #pragma unroll
            for (int k = 0; k < KPT; ++k) {
                #pragma unroll
                for (int j = 0; j < 2; ++j) {
                    float p = u[j][k].x*vc[j].x + u[j][k].y*vc[j].y
                            + u[j][k].z*vc[j].z + u[j][k].w*vc[j].w;
                    p += __shfl_xor(p, 1);   // quad butterfly: full 16-dim dot
                    p += __shfl_xor(p, 2);
                    const float e = __expf(p);
                    esum[j] += e;
                    s4[j].x += e*u[j][k].x; s4[j].y += e*u[j][k].y;
                    s4[j].z += e*u[j][k].z; s4[j].w += e*u[j][k].w;
                }
            }
        }
        // reduce over ig within the wave (lane bits 2..5), both o's for ILP
        #pragma unroll
        for (int m = 4; m <= 32; m <<= 1) {
            #pragma unroll
            for (int j = 0; j < 2; ++j) {
                s4[j].x += __shfl_xor(s4[j].x, m);
                s4[j].y += __shfl_xor(s4[j].y, m);
                s4[j].z += __shfl_xor(s4[j].z, m);
                s4[j].w += __shfl_xor(s4[j].w, m);
                esum[j] += __shfl_xor(esum[j], m);
            }
        }
        if (lane < 4) {
            #pragma unroll
            for (int j = 0; j < 2; ++j) {
                scr_s[j][wave][lane*4+0] = s4[j].x;
                scr_s[j][wave][lane*4+1] = s4[j].y;
                scr_s[j][wave][lane*4+2] = s4[j].z;
                scr_s[j][wave][lane*4+3] = s4[j].w;
                if (lane == 0) scr_e[j][wave] = esum[j];
            }
        }
        __syncthreads();
        if (tid < 32) {                      // lanes 0-15: o0, lanes 16-31: o1
            const int j = tid >> 4;
            const int d = tid & 15;
            float s = 0.f, et = 0.f;
            #pragma unroll
            for (int w = 0; w < 8; ++w) { s += scr_s[j][w][d]; et += scr_e[j][w]; }
            s /= et;                         // softmax normalization folded
            float sq = s * s;
            sq += __shfl_xor(sq, 1);         // stays within 16-lane group
            sq += __shfl_xor(sq, 2);
            sq += __shfl_xor(sq, 4);
            sq += __shfl_xor(sq, 8);
            const float nrm = sqrtf(sq);
            const float v = s * (nrm / (1.0f + sq));  // == sq*s/((1+sq)*nrm)
            if (r == 2) out[((size_t)b * N_O + o0 + j) * N_D + d] = v;
            else        vcum[j][d] += v;     // logit state: b_i = u_i . vcum
        }
        __syncthreads();
        if (r < 2) {
            vc[0] = ((const float4*)vcum[0])[d4];
            vc[1] = ((const float4*)vcum[1])[d4];
        }
    }
}

extern "C" void kernel_launch(void* const* d_in, const int* in_sizes, int n_in,
                              void* d_out, int out_size, void* d_ws, size_t ws_size,
                              hipStream_t stream)
{
    const float* u_hat = (const float*)d_in[0];
    float* out = (float*)d_out;
    const int B = in_sizes[0] / (N_I * N_O * N_D);
    hipLaunchKernelGGL(caps_route, dim3(B * 5), dim3(BLK), 0, stream, u_hat, out);
}

// Round 4
// 35.060 us; speedup vs baseline: 1.1248x; 1.1248x over previous
//
#include <hip/hip_runtime.h>
#include <math.h>

#define N_I 1152
#define N_O 10
#define N_D 16
#define BLK 256
#define KPT 18   // i-rows per thread: 1152 / (BLK/4)

// One block per (b, o). 256-thread blocks, each thread holds 18 x float4 of
// the 1152x16 u-tile in registers (72 data VGPRs). 4 blocks/CU resident
// (launch_bounds(256,4) -> 128 VGPR cap): four independent load/compute
// phase machines per CU keep the HBM pipe busy while any one block is in
// its VALU-only routing phase. r=0 partial sums fused into the load loop.
// Thread layout: d4 = tid&3 (dims 4*d4..4*d4+3), ig = tid>>2 (i = ig+64k).
__global__ __launch_bounds__(BLK, 4)
void caps_route(const float* __restrict__ u_hat, float* __restrict__ out)
{
    __shared__ float scr_s[4][16];                // per-wave partial s
    __shared__ float scr_e[4];                    // per-wave partial exp-sum
    __shared__ __align__(16) float vcum[16];      // cumulative v (= logit state)

    const int tid  = threadIdx.x;
    const int wave = tid >> 6;
    const int lane = tid & 63;
    const int d4   = tid & 3;
    const int ig   = tid >> 2;    // 0..63

    // XCD-aware swizzle: consecutive wids (same b, adjacent o) on one XCD.
    const int bid = blockIdx.x;
    const int nwg = gridDim.x;
    int wid = bid;
    if ((nwg & 7) == 0) wid = (bid & 7) * (nwg >> 3) + (bid >> 3);
    const int b = wid / N_O;
    const int o = wid - b * N_O;

    const float* gbase = u_hat + (size_t)b * (N_I * N_O * N_D)
                               + (size_t)o * N_D + d4 * 4;

    // ---- global -> registers; fuse r=0 partial sums under vmcnt ----
    float4 u[KPT];
    float4 s4 = make_float4(0.f, 0.f, 0.f, 0.f);
    #pragma unroll
    for (int k = 0; k < KPT; ++k) {
        const int i = ig + (k << 6);
        u[k] = *(const float4*)(gbase + (size_t)i * (N_O * N_D));
        s4.x += u[k].x; s4.y += u[k].y;
        s4.z += u[k].z; s4.w += u[k].w;
    }
    if (tid < 16) vcum[tid] = 0.0f;

    float4 vc = make_float4(0.f, 0.f, 0.f, 0.f);

    for (int r = 0; r < 3; ++r) {
        float esum;
        if (r == 0) {
            esum = (float)KPT;        // b == 0 -> uniform weights, e_i = 1
        } else {
            // fused: t_i = u_i . vcum ; e = exp(t_i); s += e*u ; esum += e
            s4 = make_float4(0.f, 0.f, 0.f, 0.f);
            esum = 0.0f;
            #pragma unroll
            for (int k = 0; k < KPT; ++k) {
                float p = u[k].x*vc.x + u[k].y*vc.y + u[k].z*vc.z + u[k].w*vc.w;
                p += __shfl_xor(p, 1);    // quad butterfly: full 16-dim dot
                p += __shfl_xor(p, 2);
                const float e = __expf(p);
                esum += e;
                s4.x += e*u[k].x; s4.y += e*u[k].y;
                s4.z += e*u[k].z; s4.w += e*u[k].w;
            }
        }
        // reduce over ig within the wave (lane bits 2..5)
        #pragma unroll
        for (int m = 4; m <= 32; m <<= 1) {
            s4.x += __shfl_xor(s4.x, m);
            s4.y += __shfl_xor(s4.y, m);
            s4.z += __shfl_xor(s4.z, m);
            s4.w += __shfl_xor(s4.w, m);
            esum += __shfl_xor(esum, m);
        }
        if (lane < 4) {
            scr_s[wave][lane*4+0] = s4.x;
            scr_s[wave][lane*4+1] = s4.y;
            scr_s[wave][lane*4+2] = s4.z;
            scr_s[wave][lane*4+3] = s4.w;
            if (lane == 0) scr_e[wave] = esum;
        }
        __syncthreads();
        if (tid < 16) {
            float s = 0.f, et = 0.f;
            #pragma unroll
            for (int w = 0; w < 4; ++w) { s += scr_s[w][tid]; et += scr_e[w]; }
            s /= et;                           // softmax normalization folded
            float sq = s * s;
            sq += __shfl_xor(sq, 1);
            sq += __shfl_xor(sq, 2);
            sq += __shfl_xor(sq, 4);
            sq += __shfl_xor(sq, 8);
            const float nrm = sqrtf(sq);
            const float v = s * (nrm / (1.0f + sq));   // == sq*s/((1+sq)*nrm)
            if (r == 2) out[(size_t)wid * N_D + tid] = v;
            else        vcum[tid] += v;        // logit state: b_i = u_i . vcum
        }
        __syncthreads();
        if (r < 2) vc = ((const float4*)vcum)[d4];
    }
}

extern "C" void kernel_launch(void* const* d_in, const int* in_sizes, int n_in,
                              void* d_out, int out_size, void* d_ws, size_t ws_size,
                              hipStream_t stream)
{
    const float* u_hat = (const float*)d_in[0];
    float* out = (float*)d_out;
    const int B = in_sizes[0] / (N_I * N_O * N_D);
    hipLaunchKernelGGL(caps_route, dim3(B * N_O), dim3(BLK), 0, stream, u_hat, out);
}